// Round 1
// baseline (304.595 us; speedup 1.0000x reference)
//
#include <hip/hip_runtime.h>

#define L_SEQ 1024
#define NH 16
#define HD 64
#define DMODEL 1024
#define BHS (L_SEQ * HD)   // 65536 elements per (b,h) plane of Q/K/Vt

typedef __bf16 bf16x8 __attribute__((ext_vector_type(8)));
typedef float f32x4 __attribute__((ext_vector_type(4)));

#define MFMA16(a, b, c) __builtin_amdgcn_mfma_f32_16x16x32_bf16((a), (b), (c), 0, 0, 0)

static __device__ __forceinline__ unsigned short f2b(float f) {
  unsigned int u = __builtin_bit_cast(unsigned int, f);
  u = (u + 0x7FFFu + ((u >> 16) & 1u)) >> 16;
  return (unsigned short)u;
}

static __device__ __forceinline__ bf16x8 ld8(const unsigned short* p) {
  return *(const bf16x8*)(p);
}

// ---------------- fp32 -> bf16 convert (vectorized) ----------------
__global__ __launch_bounds__(256) void k_convert(const float* __restrict__ src,
                                                 unsigned short* __restrict__ dst,
                                                 int n4) {
  int i = blockIdx.x * 256 + threadIdx.x;
  if (i < n4) {
    float4 v = *(const float4*)(src + (size_t)i * 4);
    ushort4 o;
    o.x = f2b(v.x); o.y = f2b(v.y); o.z = f2b(v.z); o.w = f2b(v.w);
    *(ushort4*)(dst + (size_t)i * 4) = o;
  }
}

// ---------------- fp32 [R][C] -> bf16 [C][R] transpose ----------------
__global__ __launch_bounds__(256) void k_transpose(const float* __restrict__ src,
                                                   unsigned short* __restrict__ dst,
                                                   int R, int C) {
  __shared__ float tile[32][33];
  const int c0 = blockIdx.x * 32, r0 = blockIdx.y * 32;
  const int tx = threadIdx.x, ty = threadIdx.y;   // block (32,8)
#pragma unroll
  for (int i = 0; i < 4; ++i)
    tile[ty + i * 8][tx] = src[(size_t)(r0 + ty + i * 8) * C + c0 + tx];
  __syncthreads();
#pragma unroll
  for (int i = 0; i < 4; ++i)
    dst[(size_t)(c0 + ty + i * 8) * R + r0 + tx] = f2b(tile[tx][ty + i * 8]);
}

// ---------------- QKV GEMM: [4096,1024] x [3072,1024]^T -> Q/K/Vt bf16 ----------------
// C[r][c] = sum_k X[r][k] * Wt[c][k].  Epilogue scatters per qkv block:
//   which=0 -> Q[b,h,l,d]; which=1 -> K[b,h,l,d]; which=2 -> Vt[b,h,d,l]
__global__ __launch_bounds__(256) void k_gemm_qkv(
    const unsigned short* __restrict__ xb,
    const unsigned short* __restrict__ wt,
    unsigned short* __restrict__ qw,
    unsigned short* __restrict__ kw,
    unsigned short* __restrict__ vtw) {
  __shared__ unsigned short As[128][40];   // +8 pad: 80B row stride, 2-way banks
  __shared__ unsigned short Bs[128][40];
  const int tid = threadIdx.x;
  const int w = tid >> 6, lane = tid & 63;
  const int wm = w >> 1, wn = w & 1;
  const int lo = lane & 15, hi = lane >> 4;
  const int m0 = blockIdx.y * 128, n0 = blockIdx.x * 128;
  const int sr = tid >> 2, sc = (tid & 3) * 8;

  f32x4 acc[4][4];
#pragma unroll
  for (int i = 0; i < 4; ++i)
#pragma unroll
    for (int j = 0; j < 4; ++j) acc[i][j] = (f32x4){0.f, 0.f, 0.f, 0.f};

  for (int kt = 0; kt < 32; ++kt) {
    const int k0 = kt * 32;
    *(uint4*)(&As[sr][sc])      = *(const uint4*)(xb + (size_t)(m0 + sr) * 1024 + k0 + sc);
    *(uint4*)(&As[sr + 64][sc]) = *(const uint4*)(xb + (size_t)(m0 + sr + 64) * 1024 + k0 + sc);
    *(uint4*)(&Bs[sr][sc])      = *(const uint4*)(wt + (size_t)(n0 + sr) * 1024 + k0 + sc);
    *(uint4*)(&Bs[sr + 64][sc]) = *(const uint4*)(wt + (size_t)(n0 + sr + 64) * 1024 + k0 + sc);
    __syncthreads();
    bf16x8 af[4], bg[4];
#pragma unroll
    for (int i = 0; i < 4; ++i) af[i] = ld8(&As[wm * 64 + i * 16 + lo][hi * 8]);
#pragma unroll
    for (int i = 0; i < 4; ++i) bg[i] = ld8(&Bs[wn * 64 + i * 16 + lo][hi * 8]);
#pragma unroll
    for (int mf = 0; mf < 4; ++mf)
#pragma unroll
      for (int nf = 0; nf < 4; ++nf)
        acc[mf][nf] = MFMA16(af[mf], bg[nf], acc[mf][nf]);
    __syncthreads();
  }

  const int which = n0 >> 10;   // uniform per block (128 | 1024)
#pragma unroll
  for (int mf = 0; mf < 4; ++mf) {
#pragma unroll
    for (int rr = 0; rr < 4; ++rr) {
      const int row = m0 + wm * 64 + mf * 16 + hi * 4 + rr;   // token index
      const int bb = row >> 10, ll = row & 1023;
#pragma unroll
      for (int nf = 0; nf < 4; ++nf) {
        const int col = n0 + wn * 64 + nf * 16 + lo;
        const int hc = col & 1023;
        const int hh = hc >> 6, dd = hc & 63;
        const unsigned short val = f2b(acc[mf][nf][rr]);
        const size_t bh = (size_t)(bb * NH + hh);
        if (which == 0)      qw[bh * BHS + ll * HD + dd] = val;
        else if (which == 1) kw[bh * BHS + ll * HD + dd] = val;
        else                 vtw[bh * BHS + dd * L_SEQ + ll] = val;
      }
    }
  }
}

// ---------------- fused attention with relative position bias ----------------
// block = 4 waves; wave w owns 16 q-rows (l0w..l0w+15); loop over 16 key tiles of 64.
__global__ __launch_bounds__(256) void k_attn(
    const unsigned short* __restrict__ qw,
    const unsigned short* __restrict__ kw,
    const unsigned short* __restrict__ vtw,
    const unsigned short* __restrict__ ew,   // [2047][64] bf16
    unsigned short* __restrict__ ow) {
  __shared__ float Gs[4][16][84];            // per-wave Q·E_band^T (band width 80)
  __shared__ unsigned short Ps[4][16][72];   // per-wave P tile (bf16), padded
  const int tid = threadIdx.x;
  const int w = tid >> 6, lane = tid & 63;
  const int lo = lane & 15, hi = lane >> 4;
  const int bh = blockIdx.x >> 4, qb = blockIdx.x & 15;
  const int q0 = qb * 64;
  const int l0w = q0 + w * 16;
  const int bb = bh >> 4, hh = bh & 15;

  // Q fragment in registers: A rows = l0w + (lane&15), k = kk*32 + (lane>>4)*8
  const unsigned short* qbase = qw + (size_t)bh * BHS + (l0w + lo) * HD;
  const bf16x8 aQ0 = ld8(qbase + hi * 8);
  const bf16x8 aQ1 = ld8(qbase + 32 + hi * 8);

  const unsigned short* kbase = kw + (size_t)bh * BHS;
  const unsigned short* vbase = vtw + (size_t)bh * BHS;

  float m_r[4], l_r[4];
  f32x4 acc_o[4];
#pragma unroll
  for (int r = 0; r < 4; ++r) { m_r[r] = -1e30f; l_r[r] = 0.f; }
#pragma unroll
  for (int d = 0; d < 4; ++d) acc_o[d] = (f32x4){0.f, 0.f, 0.f, 0.f};

  for (int kt = 0; kt < 16; ++kt) {
    const int j0 = kt * 64;
    // content scores S = Q K^T  (rows rho=(lane>>4)*4+r, cols nf*16+(lane&15))
    f32x4 acc_s[4];
#pragma unroll
    for (int nf = 0; nf < 4; ++nf) {
      const unsigned short* kr = kbase + (size_t)(j0 + nf * 16 + lo) * HD + hi * 8;
      f32x4 c = (f32x4){0.f, 0.f, 0.f, 0.f};
      c = MFMA16(aQ0, ld8(kr), c);
      c = MFMA16(aQ1, ld8(kr + 32), c);
      acc_s[nf] = c;
    }
    // pos scores: G[rho][c] = q_{l0w+rho} . E[x0 + c],  x0 = j0 - l0w + 1008
    const int x0 = j0 - l0w + 1008;
#pragma unroll
    for (int gf = 0; gf < 5; ++gf) {
      int er = x0 + gf * 16 + lo;
      er = er > 2046 ? 2046 : er;           // row 2047 only feeds unused col 79
      const unsigned short* erow = ew + (size_t)er * HD + hi * 8;
      f32x4 g = (f32x4){0.f, 0.f, 0.f, 0.f};
      g = MFMA16(aQ0, ld8(erow), g);
      g = MFMA16(aQ1, ld8(erow + 32), g);
#pragma unroll
      for (int r = 0; r < 4; ++r) Gs[w][hi * 4 + r][gf * 16 + lo] = g[r];
    }
    __syncthreads();

    // gather band: pos[rho][j] = G[rho][(j-j0) + 15 - rho], combine, scale
    float sv[4][4];
    float rmax[4];
#pragma unroll
    for (int r = 0; r < 4; ++r) rmax[r] = -1e30f;
#pragma unroll
    for (int nf = 0; nf < 4; ++nf)
#pragma unroll
      for (int r = 0; r < 4; ++r) {
        const int rho = hi * 4 + r;
        const float s = (acc_s[nf][r] + Gs[w][rho][nf * 16 + lo + 15 - rho]) * 0.125f;
        sv[nf][r] = s;
        rmax[r] = fmaxf(rmax[r], s);
      }
#pragma unroll
    for (int off = 8; off >= 1; off >>= 1)
#pragma unroll
      for (int r = 0; r < 4; ++r)
        rmax[r] = fmaxf(rmax[r], __shfl_xor(rmax[r], off));

    // online softmax update
    float corr[4], rsum[4];
#pragma unroll
    for (int r = 0; r < 4; ++r) {
      const float mn = fmaxf(m_r[r], rmax[r]);
      corr[r] = __expf(m_r[r] - mn);
      m_r[r] = mn;
      rsum[r] = 0.f;
    }
#pragma unroll
    for (int nf = 0; nf < 4; ++nf)
#pragma unroll
      for (int r = 0; r < 4; ++r) {
        const float e = __expf(sv[nf][r] - m_r[r]);
        sv[nf][r] = e;
        rsum[r] += e;
      }
#pragma unroll
    for (int off = 8; off >= 1; off >>= 1)
#pragma unroll
      for (int r = 0; r < 4; ++r)
        rsum[r] += __shfl_xor(rsum[r], off);
#pragma unroll
    for (int r = 0; r < 4; ++r) l_r[r] = l_r[r] * corr[r] + rsum[r];
#pragma unroll
    for (int d = 0; d < 4; ++d)
#pragma unroll
      for (int r = 0; r < 4; ++r) acc_o[d][r] *= corr[r];

    // route P through LDS to A-fragment layout
#pragma unroll
    for (int nf = 0; nf < 4; ++nf)
#pragma unroll
      for (int r = 0; r < 4; ++r)
        Ps[w][hi * 4 + r][nf * 16 + lo] = f2b(sv[nf][r]);
    __syncthreads();

    const bf16x8 aP0 = ld8(&Ps[w][lo][hi * 8]);
    const bf16x8 aP1 = ld8(&Ps[w][lo][32 + hi * 8]);
#pragma unroll
    for (int df = 0; df < 4; ++df) {
      const unsigned short* vr = vbase + (size_t)(df * 16 + lo) * L_SEQ + j0 + hi * 8;
      acc_o[df] = MFMA16(aP0, ld8(vr), acc_o[df]);
      acc_o[df] = MFMA16(aP1, ld8(vr + 32), acc_o[df]);
    }
    __syncthreads();
  }

  // epilogue: O / l, write [b, l, h*64+d] bf16
#pragma unroll
  for (int r = 0; r < 4; ++r) {
    const int rho = hi * 4 + r;
    const int l = q0 + w * 16 + rho;
    const float inv = 1.f / l_r[r];
    unsigned short* orow = ow + ((size_t)(bb * L_SEQ + l)) * DMODEL + hh * HD;
#pragma unroll
    for (int df = 0; df < 4; ++df)
      orow[df * 16 + lo] = f2b(acc_o[df][r] * inv);
  }
}

// ---------------- output projection: [4096,1024] x [1024,1024]^T + bias -> fp32 ----------------
__global__ __launch_bounds__(256) void k_gemm_proj(
    const unsigned short* __restrict__ ob,
    const unsigned short* __restrict__ wt,
    const float* __restrict__ bias,
    float* __restrict__ out) {
  __shared__ unsigned short As[128][40];
  __shared__ unsigned short Bs[128][40];
  const int tid = threadIdx.x;
  const int w = tid >> 6, lane = tid & 63;
  const int wm = w >> 1, wn = w & 1;
  const int lo = lane & 15, hi = lane >> 4;
  const int m0 = blockIdx.y * 128, n0 = blockIdx.x * 128;
  const int sr = tid >> 2, sc = (tid & 3) * 8;

  f32x4 acc[4][4];
#pragma unroll
  for (int i = 0; i < 4; ++i)
#pragma unroll
    for (int j = 0; j < 4; ++j) acc[i][j] = (f32x4){0.f, 0.f, 0.f, 0.f};

  for (int kt = 0; kt < 32; ++kt) {
    const int k0 = kt * 32;
    *(uint4*)(&As[sr][sc])      = *(const uint4*)(ob + (size_t)(m0 + sr) * 1024 + k0 + sc);
    *(uint4*)(&As[sr + 64][sc]) = *(const uint4*)(ob + (size_t)(m0 + sr + 64) * 1024 + k0 + sc);
    *(uint4*)(&Bs[sr][sc])      = *(const uint4*)(wt + (size_t)(n0 + sr) * 1024 + k0 + sc);
    *(uint4*)(&Bs[sr + 64][sc]) = *(const uint4*)(wt + (size_t)(n0 + sr + 64) * 1024 + k0 + sc);
    __syncthreads();
    bf16x8 af[4], bg[4];
#pragma unroll
    for (int i = 0; i < 4; ++i) af[i] = ld8(&As[wm * 64 + i * 16 + lo][hi * 8]);
#pragma unroll
    for (int i = 0; i < 4; ++i) bg[i] = ld8(&Bs[wn * 64 + i * 16 + lo][hi * 8]);
#pragma unroll
    for (int mf = 0; mf < 4; ++mf)
#pragma unroll
      for (int nf = 0; nf < 4; ++nf)
        acc[mf][nf] = MFMA16(af[mf], bg[nf], acc[mf][nf]);
    __syncthreads();
  }

#pragma unroll
  for (int mf = 0; mf < 4; ++mf) {
#pragma unroll
    for (int rr = 0; rr < 4; ++rr) {
      const int row = m0 + wm * 64 + mf * 16 + hi * 4 + rr;
#pragma unroll
      for (int nf = 0; nf < 4; ++nf) {
        const int col = n0 + wn * 64 + nf * 16 + lo;
        out[(size_t)row * 1024 + col] = acc[mf][nf][rr] + bias[col];
      }
    }
  }
}

extern "C" void kernel_launch(void* const* d_in, const int* in_sizes, int n_in,
                              void* d_out, int out_size, void* d_ws, size_t ws_size,
                              hipStream_t stream) {
  const float* x      = (const float*)d_in[0];   // [4,1024,1024]
  const float* Wqkv   = (const float*)d_in[1];   // [1024,3072]
  const float* Wproj  = (const float*)d_in[2];   // [1024,1024]
  const float* bproj  = (const float*)d_in[3];   // [1024]
  const float* relemb = (const float*)d_in[4];   // [2047,64]
  float* out = (float*)d_out;

  char* ws = (char*)d_ws;
  size_t off = 0;
  auto alloc = [&](size_t bytes) -> unsigned short* {
    unsigned short* p = (unsigned short*)(ws + off);
    off += (bytes + 255) & ~(size_t)255;
    return p;
  };
  unsigned short* xb  = alloc((size_t)4096 * 1024 * 2);   // x bf16
  unsigned short* wtq = alloc((size_t)3072 * 1024 * 2);   // W_qkv^T bf16
  unsigned short* wtp = alloc((size_t)1024 * 1024 * 2);   // W_proj^T bf16
  unsigned short* eb  = alloc((size_t)2047 * 64 * 2);     // rel_pos_emb bf16
  unsigned short* qw_ = alloc((size_t)64 * BHS * 2);      // Q [b,h,l,d]
  unsigned short* kw_ = alloc((size_t)64 * BHS * 2);      // K [b,h,l,d]
  unsigned short* vtw = alloc((size_t)64 * BHS * 2);      // V^T [b,h,d,l]
  unsigned short* ow  = alloc((size_t)4096 * 1024 * 2);   // attn out [b,l,h*d]

  k_convert<<<4096, 256, 0, stream>>>(x, xb, 1048576);
  k_convert<<<128, 256, 0, stream>>>(relemb, eb, 32752);
  k_transpose<<<dim3(96, 32), dim3(32, 8), 0, stream>>>(Wqkv, wtq, 1024, 3072);
  k_transpose<<<dim3(32, 32), dim3(32, 8), 0, stream>>>(Wproj, wtp, 1024, 1024);
  k_gemm_qkv<<<dim3(24, 32), 256, 0, stream>>>(xb, wtq, qw_, kw_, vtw);
  k_attn<<<1024, 256, 0, stream>>>(qw_, kw_, vtw, eb, ow);
  k_gemm_proj<<<dim3(8, 32), 256, 0, stream>>>(ow, wtp, bproj, out);
}

// Round 2
// 274.609 us; speedup vs baseline: 1.1092x; 1.1092x over previous
//
#include <hip/hip_runtime.h>

#define L_SEQ 1024
#define NH 16
#define HD 64
#define DMODEL 1024
#define BHS (L_SEQ * HD)   // 65536 elements per (b,h) plane of Q/K/Vt

typedef __bf16 bf16x8 __attribute__((ext_vector_type(8)));
typedef float f32x4 __attribute__((ext_vector_type(4)));

#define MFMA16(a, b, c) __builtin_amdgcn_mfma_f32_16x16x32_bf16((a), (b), (c), 0, 0, 0)

static __device__ __forceinline__ unsigned short f2b(float f) {
  unsigned int u = __builtin_bit_cast(unsigned int, f);
  u = (u + 0x7FFFu + ((u >> 16) & 1u)) >> 16;
  return (unsigned short)u;
}

static __device__ __forceinline__ bf16x8 ld8(const unsigned short* p) {
  return *(const bf16x8*)(p);
}

// ---------------- fp32 -> bf16 convert (vectorized) ----------------
__global__ __launch_bounds__(256) void k_convert(const float* __restrict__ src,
                                                 unsigned short* __restrict__ dst,
                                                 int n4) {
  int i = blockIdx.x * 256 + threadIdx.x;
  if (i < n4) {
    float4 v = *(const float4*)(src + (size_t)i * 4);
    ushort4 o;
    o.x = f2b(v.x); o.y = f2b(v.y); o.z = f2b(v.z); o.w = f2b(v.w);
    *(ushort4*)(dst + (size_t)i * 4) = o;
  }
}

// ---------------- fp32 [R][C] -> bf16 [C][R] transpose ----------------
__global__ __launch_bounds__(256) void k_transpose(const float* __restrict__ src,
                                                   unsigned short* __restrict__ dst,
                                                   int R, int C) {
  __shared__ float tile[32][33];
  const int c0 = blockIdx.x * 32, r0 = blockIdx.y * 32;
  const int tx = threadIdx.x, ty = threadIdx.y;   // block (32,8)
#pragma unroll
  for (int i = 0; i < 4; ++i)
    tile[ty + i * 8][tx] = src[(size_t)(r0 + ty + i * 8) * C + c0 + tx];
  __syncthreads();
#pragma unroll
  for (int i = 0; i < 4; ++i)
    dst[(size_t)(c0 + ty + i * 8) * R + r0 + tx] = f2b(tile[tx][ty + i * 8]);
}

// ---------------- QKV GEMM: [4096,1024] x [3072,1024]^T -> Q/K/Vt bf16 ----------------
__global__ __launch_bounds__(256) void k_gemm_qkv(
    const unsigned short* __restrict__ xb,
    const unsigned short* __restrict__ wt,
    unsigned short* __restrict__ qw,
    unsigned short* __restrict__ kw,
    unsigned short* __restrict__ vtw) {
  __shared__ unsigned short As[128][40];   // +8 pad
  __shared__ unsigned short Bs[128][40];
  const int tid = threadIdx.x;
  const int w = tid >> 6, lane = tid & 63;
  const int wm = w >> 1, wn = w & 1;
  const int lo = lane & 15, hi = lane >> 4;
  const int m0 = blockIdx.y * 128, n0 = blockIdx.x * 128;
  const int sr = tid >> 2, sc = (tid & 3) * 8;

  f32x4 acc[4][4];
#pragma unroll
  for (int i = 0; i < 4; ++i)
#pragma unroll
    for (int j = 0; j < 4; ++j) acc[i][j] = (f32x4){0.f, 0.f, 0.f, 0.f};

  for (int kt = 0; kt < 32; ++kt) {
    const int k0 = kt * 32;
    *(uint4*)(&As[sr][sc])      = *(const uint4*)(xb + (size_t)(m0 + sr) * 1024 + k0 + sc);
    *(uint4*)(&As[sr + 64][sc]) = *(const uint4*)(xb + (size_t)(m0 + sr + 64) * 1024 + k0 + sc);
    *(uint4*)(&Bs[sr][sc])      = *(const uint4*)(wt + (size_t)(n0 + sr) * 1024 + k0 + sc);
    *(uint4*)(&Bs[sr + 64][sc]) = *(const uint4*)(wt + (size_t)(n0 + sr + 64) * 1024 + k0 + sc);
    __syncthreads();
    bf16x8 af[4], bg[4];
#pragma unroll
    for (int i = 0; i < 4; ++i) af[i] = ld8(&As[wm * 64 + i * 16 + lo][hi * 8]);
#pragma unroll
    for (int i = 0; i < 4; ++i) bg[i] = ld8(&Bs[wn * 64 + i * 16 + lo][hi * 8]);
#pragma unroll
    for (int mf = 0; mf < 4; ++mf)
#pragma unroll
      for (int nf = 0; nf < 4; ++nf)
        acc[mf][nf] = MFMA16(af[mf], bg[nf], acc[mf][nf]);
    __syncthreads();
  }

  const int which = n0 >> 10;
#pragma unroll
  for (int mf = 0; mf < 4; ++mf) {
#pragma unroll
    for (int rr = 0; rr < 4; ++rr) {
      const int row = m0 + wm * 64 + mf * 16 + hi * 4 + rr;
      const int bb = row >> 10, ll = row & 1023;
#pragma unroll
      for (int nf = 0; nf < 4; ++nf) {
        const int col = n0 + wn * 64 + nf * 16 + lo;
        const int hc = col & 1023;
        const int hh = hc >> 6, dd = hc & 63;
        const unsigned short val = f2b(acc[mf][nf][rr]);
        const size_t bh = (size_t)(bb * NH + hh);
        if (which == 0)      qw[bh * BHS + ll * HD + dd] = val;
        else if (which == 1) kw[bh * BHS + ll * HD + dd] = val;
        else                 vtw[bh * BHS + dd * L_SEQ + ll] = val;
      }
    }
  }
}

// ---------------- fused attention with relative position bias ----------------
// 4 waves/block, each wave fully independent (no barriers; Gs/Ps are per-wave
// private, same-wave LDS RAW ordered by compiler lgkmcnt). All global loads
// for an iteration are issued up front so the loop has ONE latency exposure.
__global__ __launch_bounds__(256) void k_attn(
    const unsigned short* __restrict__ qw,
    const unsigned short* __restrict__ kw,
    const unsigned short* __restrict__ vtw,
    const unsigned short* __restrict__ ew,   // [2047][64] bf16
    unsigned short* __restrict__ ow) {
  __shared__ float Gs[4][16][84];            // per-wave Q·E_band^T
  __shared__ unsigned short Ps[4][16][72];   // per-wave P tile (bf16)
  const int tid = threadIdx.x;
  const int w = tid >> 6, lane = tid & 63;
  const int lo = lane & 15, hi = lane >> 4;
  const int bh = blockIdx.x >> 4, qb = blockIdx.x & 15;
  const int q0 = qb * 64;
  const int l0w = q0 + w * 16;
  const int bb = bh >> 4, hh = bh & 15;

  const unsigned short* qbase = qw + (size_t)bh * BHS + (l0w + lo) * HD;
  const bf16x8 aQ0 = ld8(qbase + hi * 8);
  const bf16x8 aQ1 = ld8(qbase + 32 + hi * 8);

  const unsigned short* kbase = kw + (size_t)bh * BHS;
  const unsigned short* vbase = vtw + (size_t)bh * BHS;

  float m_r[4], l_r[4];
  f32x4 acc_o[4];
#pragma unroll
  for (int r = 0; r < 4; ++r) { m_r[r] = -1e30f; l_r[r] = 0.f; }
#pragma unroll
  for (int d = 0; d < 4; ++d) acc_o[d] = (f32x4){0.f, 0.f, 0.f, 0.f};

  for (int kt = 0; kt < 16; ++kt) {
    const int j0 = kt * 64;

    // ---- issue ALL independent global loads up front ----
    bf16x8 kf[4][2];
#pragma unroll
    for (int nf = 0; nf < 4; ++nf) {
      const unsigned short* kr = kbase + (size_t)(j0 + nf * 16 + lo) * HD + hi * 8;
      kf[nf][0] = ld8(kr);
      kf[nf][1] = ld8(kr + 32);
    }
    bf16x8 vf[4][2];
#pragma unroll
    for (int df = 0; df < 4; ++df) {
      const unsigned short* vr = vbase + (size_t)(df * 16 + lo) * L_SEQ + j0 + hi * 8;
      vf[df][0] = ld8(vr);
      vf[df][1] = ld8(vr + 32);
    }
    const int x0 = j0 - l0w + 1008;
    bf16x8 ef[5][2];
#pragma unroll
    for (int gf = 0; gf < 5; ++gf) {
      int er = x0 + gf * 16 + lo;
      er = er > 2046 ? 2046 : er;           // row 2047 only feeds unused col 79
      const unsigned short* erow = ew + (size_t)er * HD + hi * 8;
      ef[gf][0] = ld8(erow);
      ef[gf][1] = ld8(erow + 32);
    }

    // ---- content scores S = Q K^T ----
    f32x4 acc_s[4];
#pragma unroll
    for (int nf = 0; nf < 4; ++nf) {
      f32x4 c = (f32x4){0.f, 0.f, 0.f, 0.f};
      c = MFMA16(aQ0, kf[nf][0], c);
      c = MFMA16(aQ1, kf[nf][1], c);
      acc_s[nf] = c;
    }

    // ---- pos scores G[rho][c] = q_{l0w+rho} . E[x0 + c] ----
#pragma unroll
    for (int gf = 0; gf < 5; ++gf) {
      f32x4 g = (f32x4){0.f, 0.f, 0.f, 0.f};
      g = MFMA16(aQ0, ef[gf][0], g);
      g = MFMA16(aQ1, ef[gf][1], g);
#pragma unroll
      for (int r = 0; r < 4; ++r) Gs[w][hi * 4 + r][gf * 16 + lo] = g[r];
    }

    // ---- gather band, combine, scale ----
    float sv[4][4];
    float rmax[4];
#pragma unroll
    for (int r = 0; r < 4; ++r) rmax[r] = -1e30f;
#pragma unroll
    for (int nf = 0; nf < 4; ++nf)
#pragma unroll
      for (int r = 0; r < 4; ++r) {
        const int rho = hi * 4 + r;
        const float s = (acc_s[nf][r] + Gs[w][rho][nf * 16 + lo + 15 - rho]) * 0.125f;
        sv[nf][r] = s;
        rmax[r] = fmaxf(rmax[r], s);
      }
#pragma unroll
    for (int off = 8; off >= 1; off >>= 1)
#pragma unroll
      for (int r = 0; r < 4; ++r)
        rmax[r] = fmaxf(rmax[r], __shfl_xor(rmax[r], off));

    // ---- online softmax ----
    float corr[4], rsum[4];
#pragma unroll
    for (int r = 0; r < 4; ++r) {
      const float mn = fmaxf(m_r[r], rmax[r]);
      corr[r] = __expf(m_r[r] - mn);
      m_r[r] = mn;
      rsum[r] = 0.f;
    }
#pragma unroll
    for (int nf = 0; nf < 4; ++nf)
#pragma unroll
      for (int r = 0; r < 4; ++r) {
        const float e = __expf(sv[nf][r] - m_r[r]);
        sv[nf][r] = e;
        rsum[r] += e;
      }
#pragma unroll
    for (int off = 8; off >= 1; off >>= 1)
#pragma unroll
      for (int r = 0; r < 4; ++r)
        rsum[r] += __shfl_xor(rsum[r], off);
#pragma unroll
    for (int r = 0; r < 4; ++r) l_r[r] = l_r[r] * corr[r] + rsum[r];
#pragma unroll
    for (int d = 0; d < 4; ++d)
#pragma unroll
      for (int r = 0; r < 4; ++r) acc_o[d][r] *= corr[r];

    // ---- P -> A-fragment layout via per-wave LDS (no barrier needed) ----
#pragma unroll
    for (int nf = 0; nf < 4; ++nf)
#pragma unroll
      for (int r = 0; r < 4; ++r)
        Ps[w][hi * 4 + r][nf * 16 + lo] = f2b(sv[nf][r]);

    const bf16x8 aP0 = ld8(&Ps[w][lo][hi * 8]);
    const bf16x8 aP1 = ld8(&Ps[w][lo][32 + hi * 8]);
#pragma unroll
    for (int df = 0; df < 4; ++df) {
      acc_o[df] = MFMA16(aP0, vf[df][0], acc_o[df]);
      acc_o[df] = MFMA16(aP1, vf[df][1], acc_o[df]);
    }
  }

  // epilogue: O / l, write [b, l, h*64+d] bf16
#pragma unroll
  for (int r = 0; r < 4; ++r) {
    const int rho = hi * 4 + r;
    const int l = q0 + w * 16 + rho;
    const float inv = 1.f / l_r[r];
    unsigned short* orow = ow + ((size_t)(bb * L_SEQ + l)) * DMODEL + hh * HD;
#pragma unroll
    for (int df = 0; df < 4; ++df)
      orow[df * 16 + lo] = f2b(acc_o[df][r] * inv);
  }
}

// ---------------- output projection ----------------
__global__ __launch_bounds__(256) void k_gemm_proj(
    const unsigned short* __restrict__ ob,
    const unsigned short* __restrict__ wt,
    const float* __restrict__ bias,
    float* __restrict__ out) {
  __shared__ unsigned short As[128][40];
  __shared__ unsigned short Bs[128][40];
  const int tid = threadIdx.x;
  const int w = tid >> 6, lane = tid & 63;
  const int wm = w >> 1, wn = w & 1;
  const int lo = lane & 15, hi = lane >> 4;
  const int m0 = blockIdx.y * 128, n0 = blockIdx.x * 128;
  const int sr = tid >> 2, sc = (tid & 3) * 8;

  f32x4 acc[4][4];
#pragma unroll
  for (int i = 0; i < 4; ++i)
#pragma unroll
    for (int j = 0; j < 4; ++j) acc[i][j] = (f32x4){0.f, 0.f, 0.f, 0.f};

  for (int kt = 0; kt < 32; ++kt) {
    const int k0 = kt * 32;
    *(uint4*)(&As[sr][sc])      = *(const uint4*)(ob + (size_t)(m0 + sr) * 1024 + k0 + sc);
    *(uint4*)(&As[sr + 64][sc]) = *(const uint4*)(ob + (size_t)(m0 + sr + 64) * 1024 + k0 + sc);
    *(uint4*)(&Bs[sr][sc])      = *(const uint4*)(wt + (size_t)(n0 + sr) * 1024 + k0 + sc);
    *(uint4*)(&Bs[sr + 64][sc]) = *(const uint4*)(wt + (size_t)(n0 + sr + 64) * 1024 + k0 + sc);
    __syncthreads();
    bf16x8 af[4], bg[4];
#pragma unroll
    for (int i = 0; i < 4; ++i) af[i] = ld8(&As[wm * 64 + i * 16 + lo][hi * 8]);
#pragma unroll
    for (int i = 0; i < 4; ++i) bg[i] = ld8(&Bs[wn * 64 + i * 16 + lo][hi * 8]);
#pragma unroll
    for (int mf = 0; mf < 4; ++mf)
#pragma unroll
      for (int nf = 0; nf < 4; ++nf)
        acc[mf][nf] = MFMA16(af[mf], bg[nf], acc[mf][nf]);
    __syncthreads();
  }

#pragma unroll
  for (int mf = 0; mf < 4; ++mf) {
#pragma unroll
    for (int rr = 0; rr < 4; ++rr) {
      const int row = m0 + wm * 64 + mf * 16 + hi * 4 + rr;
#pragma unroll
      for (int nf = 0; nf < 4; ++nf) {
        const int col = n0 + wn * 64 + nf * 16 + lo;
        out[(size_t)row * 1024 + col] = acc[mf][nf][rr] + bias[col];
      }
    }
  }
}

extern "C" void kernel_launch(void* const* d_in, const int* in_sizes, int n_in,
                              void* d_out, int out_size, void* d_ws, size_t ws_size,
                              hipStream_t stream) {
  const float* x      = (const float*)d_in[0];
  const float* Wqkv   = (const float*)d_in[1];
  const float* Wproj  = (const float*)d_in[2];
  const float* bproj  = (const float*)d_in[3];
  const float* relemb = (const float*)d_in[4];
  float* out = (float*)d_out;

  char* ws = (char*)d_ws;
  size_t off = 0;
  auto alloc = [&](size_t bytes) -> unsigned short* {
    unsigned short* p = (unsigned short*)(ws + off);
    off += (bytes + 255) & ~(size_t)255;
    return p;
  };
  unsigned short* xb  = alloc((size_t)4096 * 1024 * 2);
  unsigned short* wtq = alloc((size_t)3072 * 1024 * 2);
  unsigned short* wtp = alloc((size_t)1024 * 1024 * 2);
  unsigned short* eb  = alloc((size_t)2047 * 64 * 2);
  unsigned short* qw_ = alloc((size_t)64 * BHS * 2);
  unsigned short* kw_ = alloc((size_t)64 * BHS * 2);
  unsigned short* vtw = alloc((size_t)64 * BHS * 2);
  unsigned short* ow  = alloc((size_t)4096 * 1024 * 2);

  k_convert<<<4096, 256, 0, stream>>>(x, xb, 1048576);
  k_convert<<<128, 256, 0, stream>>>(relemb, eb, 32752);
  k_transpose<<<dim3(96, 32), dim3(32, 8), 0, stream>>>(Wqkv, wtq, 1024, 3072);
  k_transpose<<<dim3(32, 32), dim3(32, 8), 0, stream>>>(Wproj, wtp, 1024, 1024);
  k_gemm_qkv<<<dim3(24, 32), 256, 0, stream>>>(xb, wtq, qw_, kw_, vtw);
  k_attn<<<1024, 256, 0, stream>>>(qw_, kw_, vtw, eb, ow);
  k_gemm_proj<<<dim3(8, 32), 256, 0, stream>>>(ow, wtp, bproj, out);
}